// Round 16
// baseline (202.823 us; speedup 1.0000x reference)
//
#include <hip/hip_runtime.h>
#include <math.h>

#define BB 64
#define HH 1024
#define VV 32000
#define SRC 128
#define SLSTM 8
#define SCAT 8

typedef __attribute__((ext_vector_type(8))) __bf16 bf16x8;
typedef __attribute__((ext_vector_type(8))) unsigned short ushort8;
typedef __attribute__((ext_vector_type(4))) float f32x4;

__device__ __forceinline__ float sigmoidf_(float x){ return 1.f/(1.f+expf(-x)); }

__device__ __forceinline__ unsigned short f2bf(float f){
    union { float f; unsigned u; } v; v.f = f;
    unsigned r = v.u + 0x7FFFu + ((v.u >> 16) & 1u);   // round-to-nearest-even
    return (unsigned short)(r >> 16);
}

__device__ __forceinline__ void cvt8(const float4& x, const float4& y, unsigned short* dst){
    ushort8 s;
    s[0]=f2bf(x.x); s[1]=f2bf(x.y); s[2]=f2bf(x.z); s[3]=f2bf(x.w);
    s[4]=f2bf(y.x); s[5]=f2bf(y.y); s[6]=f2bf(y.z); s[7]=f2bf(y.w);
    *(ushort8*)dst = s;
}

// ---- 64x128 MFMA tile, 512 threads: 2-deep register prefetch, dbuf LDS ----
// One barrier per BK=64 tile; all indexing static (NT template).
template<int NT>
__device__ __forceinline__ void tile_mm(
    const int* tk, const float* A0, const float* A1,
    const float* B0, const float* B1, int K0, int ldb,
    int n0, int kbase,
    unsigned short* AsL, unsigned short* BsL, f32x4* acc)
{
    const int tid = threadIdx.x;
    const int am = tid >> 3, ak = (tid & 7) << 3;
    const int bn = tid >> 2, bk = (tid & 3) << 4;
    const int arow = tk ? tk[am] : am;
    float4 aA[2], bA[4], aB[2], bB[4];

    auto loadG = [&](int t, float4* ar, float4* br){
        int ka = kbase + (t << 6) + ak;
        const float* Ap = (ka < 1024) ? (A0 + (size_t)arow*HH + ka)
                                      : (A1 + (size_t)am*HH + (ka - 1024));
        ar[0] = *(const float4*)(Ap);
        ar[1] = *(const float4*)(Ap + 4);
        int kg = kbase + (t << 6);
        const float* Bp; int kb;
        if (kg < K0) { Bp = B0; kb = kg; } else { Bp = B1; kb = kg - K0; }
        const float* Bq = Bp + (size_t)(n0 + bn) * ldb + kb + bk;
        #pragma unroll
        for (int i = 0; i < 4; ++i) br[i] = *(const float4*)(Bq + i*4);
    };
    auto writeL = [&](int buf, const float4* ar, const float4* br){
        cvt8(ar[0], ar[1], &AsL[buf*4608 + am*72 + ak]);
        cvt8(br[0], br[1], &BsL[buf*9216 + bn*72 + bk]);
        cvt8(br[2], br[3], &BsL[buf*9216 + bn*72 + bk + 8]);
    };

    loadG(0, aA, bA);
    if (NT > 1) loadG(1, aB, bB);
    writeL(0, aA, bA);
    __syncthreads();

    const int lane = tid & 63, w = tid >> 6;
    const int lr = lane >> 4, lc = lane & 15;

    #pragma unroll
    for (int t = 0; t < NT; ++t) {
        const int cur = t & 1;
        if (t + 2 < NT) loadG(t + 2, cur ? aB : aA, cur ? bB : bA);
        #pragma unroll
        for (int ks = 0; ks < 2; ++ks) {
            bf16x8 bF = *(const bf16x8*)&BsL[cur*9216 + (w*16 + lc)*72 + ks*32 + lr*8];
            #pragma unroll
            for (int fm = 0; fm < 4; ++fm) {
                bf16x8 aF = *(const bf16x8*)&AsL[cur*4608 + (fm*16 + lc)*72 + ks*32 + lr*8];
                acc[fm] = __builtin_amdgcn_mfma_f32_16x16x32_bf16(aF, bF, acc[fm], 0, 0, 0);
            }
        }
        if (t + 1 < NT) {
            writeL(cur ^ 1, cur ? aA : aB, cur ? bA : bB);
            __syncthreads();
        }
    }
}

// ============ split-K weight GEMM (+ fused side units), 512 threads ============
// grid = (N/128, 8 [+extra]); kChunk=256; raw partials to C + y*64*N.
// EXTRA==1: y==8, x<16 -> u_e = (attn_W^T v)[1024:2048]
// EXTRA==2: y in 8..11 -> fused softmax(scores)+context
template<int GATHER, int EXTRA>
__global__ __launch_bounds__(512)
void gemm_bf(const int* __restrict__ tokens,
             const float* __restrict__ A0, const float* __restrict__ A1,
             const float* __restrict__ B0, const float* __restrict__ B1,
             int K0, int ldb, int N, float* __restrict__ C,
             const float* __restrict__ xa, const float* __restrict__ xb,
             float* __restrict__ xo)
{
    __shared__ __align__(16) unsigned short As[2*4608];
    __shared__ __align__(16) unsigned short Bs[2*9216];
    const int tid = threadIdx.x;

    if (EXTRA && blockIdx.y >= 8) {
        if (EXTRA == 1) {               // u_e[k] = sum_h attn_v[h]*attn_W[h][1024+k]
            if (blockIdx.x >= 16) return;
            float4 (*red4)[16] = (float4 (*)[16])As;
            int kq = tid & 15, hp = tid >> 4;       // hp 0..31
            int k = 1024 + blockIdx.x*64 + kq*4;
            float4 s4 = {0.f,0.f,0.f,0.f};
            for (int h = hp; h < HH; h += 32) {
                float vh = xb[h];
                float4 wv = *(const float4*)&xa[(size_t)h*2048 + k];
                s4.x = fmaf(vh, wv.x, s4.x); s4.y = fmaf(vh, wv.y, s4.y);
                s4.z = fmaf(vh, wv.z, s4.z); s4.w = fmaf(vh, wv.w, s4.w);
            }
            red4[hp][kq] = s4;
            __syncthreads();
            if (tid < 16) {
                float4 t4 = {0.f,0.f,0.f,0.f};
                #pragma unroll
                for (int i = 0; i < 32; ++i) {
                    float4 rv = red4[i][tid];
                    t4.x += rv.x; t4.y += rv.y; t4.z += rv.z; t4.w += rv.w;
                }
                *(float4*)&xo[blockIdx.x*64 + tid*4] = t4;
            }
        } else {                        // smctx: softmax(scores[b,:]) + context
            int sid = (blockIdx.y - 8)*32 + blockIdx.x;   // 0..127
            int b = sid >> 1;
            int h = ((sid & 1) << 9) + tid;
            float* wl = (float*)As;
            if (tid < SRC) wl[tid] = xa[b*SRC + tid];
            __syncthreads();
            float m = -INFINITY;
            #pragma unroll 8
            for (int l = 0; l < SRC; ++l) m = fmaxf(m, wl[l]);
            float sum = 0.f;
            #pragma unroll 8
            for (int l = 0; l < SRC; ++l) sum += expf(wl[l] - m);
            float inv = 1.f / sum;
            __syncthreads();
            if (tid < SRC) wl[tid] = expf(wl[tid] - m) * inv;
            __syncthreads();
            float a = 0.f;
            #pragma unroll 4
            for (int l = 0; l < SRC; ++l)
                a = fmaf(wl[l], xb[(size_t)(l*BB + b)*HH + h], a);
            xo[b*HH + h] = a;
        }
        return;
    }

    f32x4 acc[4] = {};
    const int n0 = blockIdx.x * 128;
    tile_mm<4>(GATHER ? tokens : nullptr, A0, A1, B0, B1, K0, ldb,
               n0, blockIdx.y * 256, As, Bs, acc);
    float* Cp = C + (size_t)blockIdx.y * 64 * N;
    const int lane = tid & 63, w = tid >> 6;
    const int lr = lane >> 4, lc = lane & 15;
    const int n = n0 + w*16 + lc;
    #pragma unroll
    for (int fm = 0; fm < 4; ++fm)
        #pragma unroll
        for (int r = 0; r < 4; ++r)
            Cp[(size_t)(fm*16 + lr*4 + r)*N + n] = acc[fm][r];
}

// ====== out-projection + FUSED log-softmax via atomic fan-in (no sub_final node) ======
// 250 blocks x 512 thr. Logits stay in registers; last-arriving block merges the
// 250x64 (m,s) partials -> lse[64]; all blocks spin on one flag, then write
// logits - lse directly (single 8.2 MB write, no round-trip).
__global__ __launch_bounds__(512)
void out_gemm(const float* __restrict__ A, const float* __restrict__ W,
              const float* __restrict__ bias, float* __restrict__ logits,
              float2* __restrict__ ms, float* __restrict__ lse_ws,
              int* __restrict__ sync_ctr, int* __restrict__ sync_flag)
{
    __shared__ __align__(16) unsigned short As[2*4608];
    __shared__ __align__(16) unsigned short Bs[2*9216];
    __shared__ float wm[8][64], wsum[8][64];
    __shared__ float lse_l[64];
    __shared__ int lastFlag;
    const int tid = threadIdx.x;
    const int n0 = blockIdx.x * 128;

    f32x4 acc[4] = {};
    tile_mm<16>(nullptr, A, A, W, W, 1 << 30, 1024, n0, 0, As, Bs, acc);

    const int lane = tid & 63, w = tid >> 6;
    const int lr = lane >> 4, lc = lane & 15;
    const int n = n0 + w*16 + lc;
    const float bv = bias[n];

    // per-block per-row (max, expsum) over this block's 128 columns
    #pragma unroll
    for (int fm = 0; fm < 4; ++fm) {
        #pragma unroll
        for (int r = 0; r < 4; ++r) {
            float v = acc[fm][r] + bv;
            float mx = v;
            #pragma unroll
            for (int o = 1; o < 16; o <<= 1) mx = fmaxf(mx, __shfl_xor(mx, o));
            float se = expf(v - mx);
            #pragma unroll
            for (int o = 1; o < 16; o <<= 1) se += __shfl_xor(se, o);
            if (lc == 0) { wm[w][fm*16 + lr*4 + r] = mx;
                           wsum[w][fm*16 + lr*4 + r] = se; }
        }
    }
    __syncthreads();
    if (tid < 64) {
        float M = wm[0][tid];
        #pragma unroll
        for (int i = 1; i < 8; ++i) M = fmaxf(M, wm[i][tid]);
        float S = 0.f;
        #pragma unroll
        for (int i = 0; i < 8; ++i) S += wsum[i][tid] * expf(wm[i][tid] - M);
        ms[blockIdx.x*64 + tid] = make_float2(M, S);
    }
    __syncthreads();

    // fan-in: last arriving block merges all partials and publishes lse
    if (tid == 0) {
        __threadfence();                               // release this block's ms
        int old = __hip_atomic_fetch_add(sync_ctr, 1, __ATOMIC_ACQ_REL,
                                         __HIP_MEMORY_SCOPE_AGENT);
        lastFlag = (old == 249);
    }
    __syncthreads();
    if (lastFlag) {
        __threadfence();                               // acquire: see all ms
        float2* red2 = (float2*)As;                    // reuse LDS (GEMM done)
        int b = tid & 63, c = tid >> 6;                // 8 chunks x 64 rows
        float m = -1e30f, s = 0.f;
        for (int i = c; i < 250; i += 8) {
            float2 p = ms[i*64 + b];
            float M = fmaxf(m, p.x);
            s = s*expf(m - M) + p.y*expf(p.x - M);
            m = M;
        }
        red2[c*64 + b] = make_float2(m, s);
        __syncthreads();
        if (tid < 64) {
            float m2 = -1e30f, s2 = 0.f;
            #pragma unroll
            for (int c2 = 0; c2 < 8; ++c2) {
                float2 p = red2[c2*64 + tid];
                float M = fmaxf(m2, p.x);
                s2 = s2*expf(m2 - M) + p.y*expf(p.x - M);
                m2 = M;
            }
            __hip_atomic_store(&lse_ws[tid], m2 + logf(s2),
                               __ATOMIC_RELAXED, __HIP_MEMORY_SCOPE_AGENT);
        }
        __syncthreads();
        if (tid == 0)
            __hip_atomic_store(sync_flag, 1, __ATOMIC_RELEASE,
                               __HIP_MEMORY_SCOPE_AGENT);
    }

    // all blocks: wait for lse, then single subtracted write
    if (tid == 0) {
        while (__hip_atomic_load(sync_flag, __ATOMIC_ACQUIRE,
                                 __HIP_MEMORY_SCOPE_AGENT) == 0)
            __builtin_amdgcn_s_sleep(2);
    }
    __syncthreads();
    if (tid < 64)
        lse_l[tid] = __hip_atomic_load(&lse_ws[tid], __ATOMIC_RELAXED,
                                       __HIP_MEMORY_SCOPE_AGENT);
    __syncthreads();
    #pragma unroll
    for (int fm = 0; fm < 4; ++fm) {
        #pragma unroll
        for (int r = 0; r < 4; ++r) {
            int row = fm*16 + lr*4 + r;
            logits[(size_t)row*VV + n] = acc[fm][r] + bv - lse_l[row];
        }
    }
}

// ---------------- LSTM pointwise (+ optional fused attention scores) ----------------
template<int WITH_SCORES>
__global__ __launch_bounds__(256)
void lstm_point(const float* __restrict__ gates,   // [SLSTM][64][4096]
                const float* __restrict__ bih, const float* __restrict__ bhh,
                const float* __restrict__ c0,
                float* __restrict__ hn, float* __restrict__ cn,
                float* __restrict__ hout,
                const float* __restrict__ u_e, const float* __restrict__ enc,
                float* __restrict__ scores)
{
    int bid = blockIdx.x;
    if (WITH_SCORES && bid >= 256) {
        // scores[b,l] = u_e . enc[l,b,:]  (h/bias score terms cancel in softmax)
        int g = (bid - 256)*4 + (threadIdx.x >> 6);   // 0..2047, 4 pairs each
        int lane = threadIdx.x & 63;
        #pragma unroll
        for (int q = 0; q < 4; ++q) {
            int p = g*4 + q;
            int b = p >> 7, l = p & 127;
            const float* e = enc + (size_t)(l*BB + b)*HH;
            float s = 0.f;
            #pragma unroll
            for (int t = 0; t < 16; ++t)
                s = fmaf(u_e[lane + 64*t], e[lane + 64*t], s);
            #pragma unroll
            for (int o = 32; o > 0; o >>= 1) s += __shfl_xor(s, o);
            if (lane == 0) scores[b*SRC + l] = s;
        }
        return;
    }
    int idx = bid*256 + threadIdx.x;     // 0..65535
    int b = idx >> 10, k = idx & 1023;
    const float* g = gates + b*4096;
    float ig = bih[k]        + bhh[k];
    float fg = bih[1024 + k] + bhh[1024 + k];
    float gg = bih[2048 + k] + bhh[2048 + k];
    float og = bih[3072 + k] + bhh[3072 + k];
    #pragma unroll
    for (int s = 0; s < SLSTM; ++s) {
        const float* gs = g + s*BB*4096;
        ig += gs[k];
        fg += gs[1024 + k];
        gg += gs[2048 + k];
        og += gs[3072 + k];
    }
    float c = sigmoidf_(fg)*c0[b*HH + k] + sigmoidf_(ig)*tanhf(gg);
    float h = sigmoidf_(og)*tanhf(c);
    cn[b*HH + k] = c;
    hn[b*HH + k] = h;
    hout[b*HH + k] = h;
}

// -------- concat reduce + bias + tanh (SCAT partials); also resets fan-in sync --------
__global__ __launch_bounds__(256)
void reduce_tanh(const float* __restrict__ P,   // [SCAT][64][1024]
                 const float* __restrict__ bias, float* __restrict__ out,
                 int* __restrict__ sync_ctr, int* __restrict__ sync_flag)
{
    if (blockIdx.x == 0 && threadIdx.x == 0) {
        __hip_atomic_store(sync_ctr, 0, __ATOMIC_RELAXED, __HIP_MEMORY_SCOPE_AGENT);
        __hip_atomic_store(sync_flag, 0, __ATOMIC_RELAXED, __HIP_MEMORY_SCOPE_AGENT);
    }
    int idx = blockIdx.x*256 + threadIdx.x;     // 0..65535
    int n = idx & 1023;
    float s = bias[n];
    #pragma unroll
    for (int si = 0; si < SCAT; ++si) s += P[si*65536 + idx];
    out[idx] = tanhf(s);
}

// ================================================================
extern "C" void kernel_launch(void* const* d_in, const int* in_sizes, int n_in,
                              void* d_out, int out_size, void* d_ws, size_t ws_size,
                              hipStream_t stream)
{
    const int*   tokens   = (const int*)  d_in[0];
    const float* h0       = (const float*)d_in[1];
    const float* c0       = (const float*)d_in[2];
    const float* enc      = (const float*)d_in[3];
    const float* emb      = (const float*)d_in[4];
    const float* W_ih     = (const float*)d_in[5];
    const float* W_hh     = (const float*)d_in[6];
    const float* b_ih     = (const float*)d_in[7];
    const float* b_hh     = (const float*)d_in[8];
    const float* attn_W   = (const float*)d_in[9];
    const float* attn_v   = (const float*)d_in[11];
    const float* concat_W = (const float*)d_in[12];
    const float* concat_b = (const float*)d_in[13];
    const float* out_W    = (const float*)d_in[14];
    const float* out_b    = (const float*)d_in[15];

    float* out  = (float*)d_out;
    float* logp = out;                      // [64, 32000]
    float* h_n  = out + (size_t)BB*VV;      // [2, 64, 1024]
    float* c_n  = h_n + 2*BB*HH;            // [2, 64, 1024]

    // workspace layout (floats)
    float* ws     = (float*)d_ws;
    float* gates  = ws;                       // [SLSTM=8][64][4096] partials
    float* catP   = gates + SLSTM*262144;     // [SCAT=8][64][1024] partials
    float* h1     = catP  + SCAT*65536;       // [64][1024]
    float* h_top  = h1    + 65536;            // [64][1024]
    float* ctx    = h_top + 65536;            // [64][1024]
    float* h_c    = ctx   + 65536;            // [64][1024]
    float* u_e    = h_c   + 65536;            // [1024]
    float* scores = u_e   + 1024;             // [64][128]
    float2* ms    = (float2*)(scores + 8192); // [250][64] (m, s)
    float* lse_ws = (float*)(ms + 250*64);    // [64]
    int*  syncp   = (int*)(lse_ws + 128);     // counter, flag (padded away from lse)

    // 1) LSTM L0 GEMM (A = [emb[tok] ; h0[0]] gathered inline) + u_e side-blocks
    gemm_bf<1,1><<<dim3(32, 9), 512, 0, stream>>>(
        tokens, emb, h0, W_ih, W_hh, 1024, 1024, 4096, gates,
        attn_W, attn_v, u_e);

    // 2) LSTM L0 pointwise + attention scores (independent; fused grid)
    lstm_point<1><<<768, 256, 0, stream>>>(gates, b_ih, b_hh, c0,
                                           h_n, c_n, h1, u_e, enc, scores);

    // 3) LSTM L1 GEMM (A = [h1 ; h0[1]]) + fused softmax/context side-blocks
    gemm_bf<0,2><<<dim3(32, 12), 512, 0, stream>>>(
        nullptr, h1, h0 + BB*HH,
        W_ih + (size_t)4096*1024, W_hh + (size_t)4096*1024, 1024, 1024,
        4096, gates, scores, enc, ctx);

    // 4) LSTM L1 pointwise
    lstm_point<0><<<256, 256, 0, stream>>>(gates, b_ih + 4096, b_hh + 4096, c0 + BB*HH,
                                           h_n + BB*HH, c_n + BB*HH, h_top,
                                           nullptr, nullptr, nullptr);

    // 5) concat GEMM (A = [ctx ; h_top], K=2048) -> catP partials
    gemm_bf<0,0><<<dim3(8, 8), 512, 0, stream>>>(
        nullptr, ctx, h_top, concat_W, nullptr, 1 << 30, 2048,
        1024, catP, nullptr, nullptr, nullptr);

    // 6) reduce + bias + tanh -> h_c; resets out_gemm's fan-in counter/flag
    reduce_tanh<<<256, 256, 0, stream>>>(catP, concat_b, h_c, syncp, syncp + 1);

    // 7) out-projection + fused lse + subtraction (atomic fan-in, single write)
    out_gemm<<<250, 512, 0, stream>>>(h_c, out_W, out_b, logp, ms,
                                      lse_ws, syncp, syncp + 1);
}

// Round 17
// 200.249 us; speedup vs baseline: 1.0129x; 1.0129x over previous
//
#include <hip/hip_runtime.h>
#include <math.h>

#define BB 64
#define HH 1024
#define VV 32000
#define SRC 128
#define SLSTM 8
#define SCAT 8

typedef __attribute__((ext_vector_type(8))) __bf16 bf16x8;
typedef __attribute__((ext_vector_type(8))) unsigned short ushort8;
typedef __attribute__((ext_vector_type(4))) float f32x4;

__device__ __forceinline__ float sigmoidf_(float x){ return 1.f/(1.f+expf(-x)); }

__device__ __forceinline__ unsigned short f2bf(float f){
    union { float f; unsigned u; } v; v.f = f;
    unsigned r = v.u + 0x7FFFu + ((v.u >> 16) & 1u);   // round-to-nearest-even
    return (unsigned short)(r >> 16);
}

__device__ __forceinline__ void cvt8(const float4& x, const float4& y, unsigned short* dst){
    ushort8 s;
    s[0]=f2bf(x.x); s[1]=f2bf(x.y); s[2]=f2bf(x.z); s[3]=f2bf(x.w);
    s[4]=f2bf(y.x); s[5]=f2bf(y.y); s[6]=f2bf(y.z); s[7]=f2bf(y.w);
    *(ushort8*)dst = s;
}

// ---- 64x128 MFMA tile, 512 threads: 2-deep register prefetch, dbuf LDS ----
// One barrier per BK=64 tile; all indexing static (NT template).
template<int NT>
__device__ __forceinline__ void tile_mm(
    const int* tk, const float* A0, const float* A1,
    const float* B0, const float* B1, int K0, int ldb,
    int n0, int kbase,
    unsigned short* AsL, unsigned short* BsL, f32x4* acc)
{
    const int tid = threadIdx.x;
    const int am = tid >> 3, ak = (tid & 7) << 3;
    const int bn = tid >> 2, bk = (tid & 3) << 4;
    const int arow = tk ? tk[am] : am;
    float4 aA[2], bA[4], aB[2], bB[4];

    auto loadG = [&](int t, float4* ar, float4* br){
        int ka = kbase + (t << 6) + ak;
        const float* Ap = (ka < 1024) ? (A0 + (size_t)arow*HH + ka)
                                      : (A1 + (size_t)am*HH + (ka - 1024));
        ar[0] = *(const float4*)(Ap);
        ar[1] = *(const float4*)(Ap + 4);
        int kg = kbase + (t << 6);
        const float* Bp; int kb;
        if (kg < K0) { Bp = B0; kb = kg; } else { Bp = B1; kb = kg - K0; }
        const float* Bq = Bp + (size_t)(n0 + bn) * ldb + kb + bk;
        #pragma unroll
        for (int i = 0; i < 4; ++i) br[i] = *(const float4*)(Bq + i*4);
    };
    auto writeL = [&](int buf, const float4* ar, const float4* br){
        cvt8(ar[0], ar[1], &AsL[buf*4608 + am*72 + ak]);
        cvt8(br[0], br[1], &BsL[buf*9216 + bn*72 + bk]);
        cvt8(br[2], br[3], &BsL[buf*9216 + bn*72 + bk + 8]);
    };

    loadG(0, aA, bA);
    if (NT > 1) loadG(1, aB, bB);
    writeL(0, aA, bA);
    __syncthreads();

    const int lane = tid & 63, w = tid >> 6;
    const int lr = lane >> 4, lc = lane & 15;

    #pragma unroll
    for (int t = 0; t < NT; ++t) {
        const int cur = t & 1;
        if (t + 2 < NT) loadG(t + 2, cur ? aB : aA, cur ? bB : bA);
        #pragma unroll
        for (int ks = 0; ks < 2; ++ks) {
            bf16x8 bF = *(const bf16x8*)&BsL[cur*9216 + (w*16 + lc)*72 + ks*32 + lr*8];
            #pragma unroll
            for (int fm = 0; fm < 4; ++fm) {
                bf16x8 aF = *(const bf16x8*)&AsL[cur*4608 + (fm*16 + lc)*72 + ks*32 + lr*8];
                acc[fm] = __builtin_amdgcn_mfma_f32_16x16x32_bf16(aF, bF, acc[fm], 0, 0, 0);
            }
        }
        if (t + 1 < NT) {
            writeL(cur ^ 1, cur ? aA : aB, cur ? bA : bB);
            __syncthreads();
        }
    }
}

// ============ split-K weight GEMM (+ fused side units), 512 threads ============
// grid = (N/128, 8 [+extra]); kChunk=256; raw partials to C + y*64*N.
// EXTRA==1: y==8, x<16 -> u_e = (attn_W^T v)[1024:2048]
// EXTRA==2: y in 8..11 -> fused softmax(scores)+context
template<int GATHER, int EXTRA>
__global__ __launch_bounds__(512)
void gemm_bf(const int* __restrict__ tokens,
             const float* __restrict__ A0, const float* __restrict__ A1,
             const float* __restrict__ B0, const float* __restrict__ B1,
             int K0, int ldb, int N, float* __restrict__ C,
             const float* __restrict__ xa, const float* __restrict__ xb,
             float* __restrict__ xo)
{
    __shared__ __align__(16) unsigned short As[2*4608];
    __shared__ __align__(16) unsigned short Bs[2*9216];
    const int tid = threadIdx.x;

    if (EXTRA && blockIdx.y >= 8) {
        if (EXTRA == 1) {               // u_e[k] = sum_h attn_v[h]*attn_W[h][1024+k]
            if (blockIdx.x >= 16) return;
            float4 (*red4)[16] = (float4 (*)[16])As;
            int kq = tid & 15, hp = tid >> 4;       // hp 0..31
            int k = 1024 + blockIdx.x*64 + kq*4;
            float4 s4 = {0.f,0.f,0.f,0.f};
            for (int h = hp; h < HH; h += 32) {
                float vh = xb[h];
                float4 wv = *(const float4*)&xa[(size_t)h*2048 + k];
                s4.x = fmaf(vh, wv.x, s4.x); s4.y = fmaf(vh, wv.y, s4.y);
                s4.z = fmaf(vh, wv.z, s4.z); s4.w = fmaf(vh, wv.w, s4.w);
            }
            red4[hp][kq] = s4;
            __syncthreads();
            if (tid < 16) {
                float4 t4 = {0.f,0.f,0.f,0.f};
                #pragma unroll
                for (int i = 0; i < 32; ++i) {
                    float4 rv = red4[i][tid];
                    t4.x += rv.x; t4.y += rv.y; t4.z += rv.z; t4.w += rv.w;
                }
                *(float4*)&xo[blockIdx.x*64 + tid*4] = t4;
            }
        } else {                        // smctx: softmax(scores[b,:]) + context
            int sid = (blockIdx.y - 8)*32 + blockIdx.x;   // 0..127
            int b = sid >> 1;
            int h = ((sid & 1) << 9) + tid;
            float* wl = (float*)As;
            if (tid < SRC) wl[tid] = xa[b*SRC + tid];
            __syncthreads();
            float m = -INFINITY;
            #pragma unroll 8
            for (int l = 0; l < SRC; ++l) m = fmaxf(m, wl[l]);
            float sum = 0.f;
            #pragma unroll 8
            for (int l = 0; l < SRC; ++l) sum += expf(wl[l] - m);
            float inv = 1.f / sum;
            __syncthreads();
            if (tid < SRC) wl[tid] = expf(wl[tid] - m) * inv;
            __syncthreads();
            float a = 0.f;
            #pragma unroll 4
            for (int l = 0; l < SRC; ++l)
                a = fmaf(wl[l], xb[(size_t)(l*BB + b)*HH + h], a);
            xo[b*HH + h] = a;
        }
        return;
    }

    f32x4 acc[4] = {};
    const int n0 = blockIdx.x * 128;
    tile_mm<4>(GATHER ? tokens : nullptr, A0, A1, B0, B1, K0, ldb,
               n0, blockIdx.y * 256, As, Bs, acc);
    float* Cp = C + (size_t)blockIdx.y * 64 * N;
    const int lane = tid & 63, w = tid >> 6;
    const int lr = lane >> 4, lc = lane & 15;
    const int n = n0 + w*16 + lc;
    #pragma unroll
    for (int fm = 0; fm < 4; ++fm)
        #pragma unroll
        for (int r = 0; r < 4; ++r)
            Cp[(size_t)(fm*16 + lr*4 + r)*N + n] = acc[fm][r];
}

// ====== out-projection + fused log-softmax, spill-free fan-in ======
// 250 blocks x 512 thr. Epilogue writes UNSUBTRACTED logits immediately (ends
// acc live range -> no spill across the sync section, the R16 failure mode),
// publishes per-block (m,s); last-arriving block merges -> lse; all blocks then
// re-read their own L2-hot lines and subtract in place.
__global__ __launch_bounds__(512)
void out_gemm(const float* __restrict__ A, const float* __restrict__ W,
              const float* __restrict__ bias, float* __restrict__ logits,
              float2* __restrict__ ms, float* __restrict__ lse_ws,
              int* __restrict__ sync_ctr, int* __restrict__ sync_flag)
{
    __shared__ __align__(16) unsigned short As[2*4608];
    __shared__ __align__(16) unsigned short Bs[2*9216];
    __shared__ float wm[8][64], wsum[8][64];
    __shared__ float lse_l[64];
    __shared__ int lastFlag;
    const int tid = threadIdx.x;
    const int n0 = blockIdx.x * 128;

    {
        f32x4 acc[4] = {};
        tile_mm<16>(nullptr, A, A, W, W, 1 << 30, 1024, n0, 0, As, Bs, acc);

        const int lane = tid & 63, w = tid >> 6;
        const int lr = lane >> 4, lc = lane & 15;
        const int n = n0 + w*16 + lc;
        const float bv = bias[n];
        #pragma unroll
        for (int fm = 0; fm < 4; ++fm) {
            #pragma unroll
            for (int r = 0; r < 4; ++r) {
                float v = acc[fm][r] + bv;
                logits[(size_t)(fm*16 + lr*4 + r)*VV + n] = v;   // unsubtracted
                float mx = v;
                #pragma unroll
                for (int o = 1; o < 16; o <<= 1) mx = fmaxf(mx, __shfl_xor(mx, o));
                float se = expf(v - mx);
                #pragma unroll
                for (int o = 1; o < 16; o <<= 1) se += __shfl_xor(se, o);
                if (lc == 0) { wm[w][fm*16 + lr*4 + r] = mx;
                               wsum[w][fm*16 + lr*4 + r] = se; }
            }
        }
        __syncthreads();
        if (tid < 64) {
            float M = wm[0][tid];
            #pragma unroll
            for (int i = 1; i < 8; ++i) M = fmaxf(M, wm[i][tid]);
            float S = 0.f;
            #pragma unroll
            for (int i = 0; i < 8; ++i) S += wsum[i][tid] * expf(wm[i][tid] - M);
            ms[blockIdx.x*64 + tid] = make_float2(M, S);
        }
        __syncthreads();
    }   // acc, staging, bv all dead here — nothing heavy lives across the sync

    // fan-in: last arriving block merges all partials and publishes lse
    if (tid == 0) {
        __threadfence();                               // release ms (+ logits)
        int old = __hip_atomic_fetch_add(sync_ctr, 1, __ATOMIC_ACQ_REL,
                                         __HIP_MEMORY_SCOPE_AGENT);
        lastFlag = (old == 249);
    }
    __syncthreads();
    if (lastFlag) {
        __threadfence();                               // acquire: see all ms
        float2* red2 = (float2*)As;                    // reuse LDS (GEMM done)
        int b = tid & 63, c = tid >> 6;                // 8 chunks x 64 rows
        float m = -1e30f, s = 0.f;
        for (int i = c; i < 250; i += 8) {
            float2 p = ms[i*64 + b];
            float M = fmaxf(m, p.x);
            s = s*expf(m - M) + p.y*expf(p.x - M);
            m = M;
        }
        red2[c*64 + b] = make_float2(m, s);
        __syncthreads();
        if (tid < 64) {
            float m2 = -1e30f, s2 = 0.f;
            #pragma unroll
            for (int c2 = 0; c2 < 8; ++c2) {
                float2 p = red2[c2*64 + tid];
                float M = fmaxf(m2, p.x);
                s2 = s2*expf(m2 - M) + p.y*expf(p.x - M);
                m2 = M;
            }
            __hip_atomic_store(&lse_ws[tid], m2 + logf(s2),
                               __ATOMIC_RELAXED, __HIP_MEMORY_SCOPE_AGENT);
        }
        __syncthreads();
        if (tid == 0)
            __hip_atomic_store(sync_flag, 1, __ATOMIC_RELEASE,
                               __HIP_MEMORY_SCOPE_AGENT);
    }

    // all blocks: wait for lse, then subtract on own (L2-hot) lines
    if (tid == 0) {
        while (__hip_atomic_load(sync_flag, __ATOMIC_ACQUIRE,
                                 __HIP_MEMORY_SCOPE_AGENT) == 0)
            __builtin_amdgcn_s_sleep(2);
    }
    __syncthreads();
    if (tid < 64)
        lse_l[tid] = __hip_atomic_load(&lse_ws[tid], __ATOMIC_RELAXED,
                                       __HIP_MEMORY_SCOPE_AGENT);
    __syncthreads();
    {
        const int lane = tid & 63, w = tid >> 6;
        const int lr = lane >> 4, lc = lane & 15;
        const int n = n0 + w*16 + lc;
        #pragma unroll
        for (int fm = 0; fm < 4; ++fm) {
            #pragma unroll
            for (int r = 0; r < 4; ++r) {
                int row = fm*16 + lr*4 + r;
                size_t off = (size_t)row*VV + n;
                logits[off] -= lse_l[row];             // own block's lines, L2-hot
            }
        }
    }
}

// ---------------- LSTM pointwise (+ optional fused attention scores) ----------------
template<int WITH_SCORES>
__global__ __launch_bounds__(256)
void lstm_point(const float* __restrict__ gates,   // [SLSTM][64][4096]
                const float* __restrict__ bih, const float* __restrict__ bhh,
                const float* __restrict__ c0,
                float* __restrict__ hn, float* __restrict__ cn,
                float* __restrict__ hout,
                const float* __restrict__ u_e, const float* __restrict__ enc,
                float* __restrict__ scores)
{
    int bid = blockIdx.x;
    if (WITH_SCORES && bid >= 256) {
        // scores[b,l] = u_e . enc[l,b,:]  (h/bias score terms cancel in softmax)
        int g = (bid - 256)*4 + (threadIdx.x >> 6);   // 0..2047, 4 pairs each
        int lane = threadIdx.x & 63;
        #pragma unroll
        for (int q = 0; q < 4; ++q) {
            int p = g*4 + q;
            int b = p >> 7, l = p & 127;
            const float* e = enc + (size_t)(l*BB + b)*HH;
            float s = 0.f;
            #pragma unroll
            for (int t = 0; t < 16; ++t)
                s = fmaf(u_e[lane + 64*t], e[lane + 64*t], s);
            #pragma unroll
            for (int o = 32; o > 0; o >>= 1) s += __shfl_xor(s, o);
            if (lane == 0) scores[b*SRC + l] = s;
        }
        return;
    }
    int idx = bid*256 + threadIdx.x;     // 0..65535
    int b = idx >> 10, k = idx & 1023;
    const float* g = gates + b*4096;
    float ig = bih[k]        + bhh[k];
    float fg = bih[1024 + k] + bhh[1024 + k];
    float gg = bih[2048 + k] + bhh[2048 + k];
    float og = bih[3072 + k] + bhh[3072 + k];
    #pragma unroll
    for (int s = 0; s < SLSTM; ++s) {
        const float* gs = g + s*BB*4096;
        ig += gs[k];
        fg += gs[1024 + k];
        gg += gs[2048 + k];
        og += gs[3072 + k];
    }
    float c = sigmoidf_(fg)*c0[b*HH + k] + sigmoidf_(ig)*tanhf(gg);
    float h = sigmoidf_(og)*tanhf(c);
    cn[b*HH + k] = c;
    hn[b*HH + k] = h;
    hout[b*HH + k] = h;
}

// -------- concat reduce + bias + tanh (SCAT partials); also resets fan-in sync --------
__global__ __launch_bounds__(256)
void reduce_tanh(const float* __restrict__ P,   // [SCAT][64][1024]
                 const float* __restrict__ bias, float* __restrict__ out,
                 int* __restrict__ sync_ctr, int* __restrict__ sync_flag)
{
    if (blockIdx.x == 0 && threadIdx.x == 0) {
        __hip_atomic_store(sync_ctr, 0, __ATOMIC_RELAXED, __HIP_MEMORY_SCOPE_AGENT);
        __hip_atomic_store(sync_flag, 0, __ATOMIC_RELAXED, __HIP_MEMORY_SCOPE_AGENT);
    }
    int idx = blockIdx.x*256 + threadIdx.x;     // 0..65535
    int n = idx & 1023;
    float s = bias[n];
    #pragma unroll
    for (int si = 0; si < SCAT; ++si) s += P[si*65536 + idx];
    out[idx] = tanhf(s);
}

// ================================================================
extern "C" void kernel_launch(void* const* d_in, const int* in_sizes, int n_in,
                              void* d_out, int out_size, void* d_ws, size_t ws_size,
                              hipStream_t stream)
{
    const int*   tokens   = (const int*)  d_in[0];
    const float* h0       = (const float*)d_in[1];
    const float* c0       = (const float*)d_in[2];
    const float* enc      = (const float*)d_in[3];
    const float* emb      = (const float*)d_in[4];
    const float* W_ih     = (const float*)d_in[5];
    const float* W_hh     = (const float*)d_in[6];
    const float* b_ih     = (const float*)d_in[7];
    const float* b_hh     = (const float*)d_in[8];
    const float* attn_W   = (const float*)d_in[9];
    const float* attn_v   = (const float*)d_in[11];
    const float* concat_W = (const float*)d_in[12];
    const float* concat_b = (const float*)d_in[13];
    const float* out_W    = (const float*)d_in[14];
    const float* out_b    = (const float*)d_in[15];

    float* out  = (float*)d_out;
    float* logp = out;                      // [64, 32000]
    float* h_n  = out + (size_t)BB*VV;      // [2, 64, 1024]
    float* c_n  = h_n + 2*BB*HH;            // [2, 64, 1024]

    // workspace layout (floats)
    float* ws     = (float*)d_ws;
    float* gates  = ws;                       // [SLSTM=8][64][4096] partials
    float* catP   = gates + SLSTM*262144;     // [SCAT=8][64][1024] partials
    float* h1     = catP  + SCAT*65536;       // [64][1024]
    float* h_top  = h1    + 65536;            // [64][1024]
    float* ctx    = h_top + 65536;            // [64][1024]
    float* h_c    = ctx   + 65536;            // [64][1024]
    float* u_e    = h_c   + 65536;            // [1024]
    float* scores = u_e   + 1024;             // [64][128]
    float2* ms    = (float2*)(scores + 8192); // [250][64] (m, s)
    float* lse_ws = (float*)(ms + 250*64);    // [64]
    int*  syncp   = (int*)(lse_ws + 128);     // counter, flag

    // 1) LSTM L0 GEMM (A = [emb[tok] ; h0[0]] gathered inline) + u_e side-blocks
    gemm_bf<1,1><<<dim3(32, 9), 512, 0, stream>>>(
        tokens, emb, h0, W_ih, W_hh, 1024, 1024, 4096, gates,
        attn_W, attn_v, u_e);

    // 2) LSTM L0 pointwise + attention scores (independent; fused grid)
    lstm_point<1><<<768, 256, 0, stream>>>(gates, b_ih, b_hh, c0,
                                           h_n, c_n, h1, u_e, enc, scores);

    // 3) LSTM L1 GEMM (A = [h1 ; h0[1]]) + fused softmax/context side-blocks
    gemm_bf<0,2><<<dim3(32, 12), 512, 0, stream>>>(
        nullptr, h1, h0 + BB*HH,
        W_ih + (size_t)4096*1024, W_hh + (size_t)4096*1024, 1024, 1024,
        4096, gates, scores, enc, ctx);

    // 4) LSTM L1 pointwise
    lstm_point<0><<<256, 256, 0, stream>>>(gates, b_ih + 4096, b_hh + 4096, c0 + BB*HH,
                                           h_n + BB*HH, c_n + BB*HH, h_top,
                                           nullptr, nullptr, nullptr);

    // 5) concat GEMM (A = [ctx ; h_top], K=2048) -> catP partials
    gemm_bf<0,0><<<dim3(8, 8), 512, 0, stream>>>(
        nullptr, ctx, h_top, concat_W, nullptr, 1 << 30, 2048,
        1024, catP, nullptr, nullptr, nullptr);

    // 6) reduce + bias + tanh -> h_c; resets out_gemm's fan-in counter/flag
    reduce_tanh<<<256, 256, 0, stream>>>(catP, concat_b, h_c, syncp, syncp + 1);

    // 7) out-projection + fused lse + in-place subtract (spill-free fan-in)
    out_gemm<<<250, 512, 0, stream>>>(h_c, out_W, out_b, logp, ms,
                                      lse_ws, syncp, syncp + 1);
}